// Round 13
// baseline (303.992 us; speedup 1.0000x reference)
//
#include <hip/hip_runtime.h>
#include <hip/hip_bf16.h>
#include <math.h>

#define Bb 64
#define Nn 128
#define FNf 64
#define Ss 1033
#define EMBe 50

typedef float f4 __attribute__((ext_vector_type(4)));
typedef float f2 __attribute__((ext_vector_type(2)));
typedef int   i4 __attribute__((ext_vector_type(4)));

// hs layout: [b][k][s] with padded strides for 16B-aligned f4 stores
#define HS_KSTRIDE 1036
#define HS_BSTRIDE 8288   // 8*1036
#define HS_PSIZE   530432 // 64*8288

// ---- workspace offsets (in floats) ----
constexpr size_t OFF_EMSG  = 2*524288 + 2*524288;       // 2 * 524288  (edge_msg)
constexpr size_t OFF_MASK  = OFF_EMSG  + 2*524288;      // (unused)
constexpr size_t OFF_OUT12 = OFF_MASK  + 2*8192;        // 2 * 8192    (graph readouts)
constexpr size_t OFF_PPRE  = OFF_OUT12 + 2*8192;        // 2 * 16384   (dec1 pre-act accum)
constexpr size_t OFF_PBN   = OFF_PPRE  + 2*16384;       // (unused)
constexpr size_t OFF_XW    = OFF_PBN   + 2*16384;       // 2 * 2115584 (log2e-scaled x@W_ih.T + biases, permuted)
constexpr size_t OFF_HS    = OFF_XW    + 2*2115584;     // 2 * HS_PSIZE (LSTM hidden seq, [b][k][s])
constexpr size_t OFF_W2F   = OFF_HS    + 2*HS_PSIZE;    // 2 * 256
constexpr size_t OFF_WMF   = OFF_W2F   + 2*256;         // 2 * 200
constexpr size_t OFF_WSF   = OFF_WMF   + 2*200;         // 963
constexpr size_t OFF_CONST = OFF_WSF   + 964;           // 4
constexpr size_t OFF_COUNT = OFF_CONST + 4;             // 2 * 8192 (int)
constexpr size_t OFF_NZ    = OFF_COUNT + 2*8192;        // 2 * 524288 (int, zero-padded per row)
constexpr size_t OFF_AVAL  = OFF_NZ    + 2*524288;      // 2 * 524288 (zero-padded per row)

__device__ inline f4 relu4(f4 v) {
  v[0] = fmaxf(v[0], 0.f); v[1] = fmaxf(v[1], 0.f);
  v[2] = fmaxf(v[2], 0.f); v[3] = fmaxf(v[3], 0.f);
  return v;
}

// DPP row rotate-right: dst[i] = src[(i - n) & 15] within each 16-lane row.
#define ROR16(x, n) __int_as_float(__builtin_amdgcn_update_dpp(0, __float_as_int(x), 0x120 + (n), 0xF, 0xF, true))

// ================= kA: k1 (0..4095) + k6 (4096..8227) + fold (8228) + zero (8229..8244)
__global__ __launch_bounds__(256) void kA(
    const float* __restrict__ adj1, const float* __restrict__ adj2,
    const float* __restrict__ edges1, const float* __restrict__ edges2,
    const float* __restrict__ We1, const float* __restrict__ We2,
    const int* __restrict__ ids1, const int* __restrict__ ids2,
    const float* __restrict__ we, const float* __restrict__ pe,
    const float* __restrict__ lng, const float* __restrict__ lnb,
    const float* __restrict__ Wih, const float* __restrict__ bih,
    const float* __restrict__ bhh,
    const float* __restrict__ W2, const float* __restrict__ b2,
    const float* __restrict__ Wm, const float* __restrict__ bm,
    const float* __restrict__ Wsd, const float* __restrict__ bsd,
    const float* __restrict__ Wf, const float* __restrict__ bf,
    float* __restrict__ ws) {
  int bid = blockIdx.x;
  int t = threadIdx.x;
  if (bid < 4096) {
    // ---------------- k1: adjacency compaction + edge_msg ----------------
    int g = bid >> 11;
    int w = t >> 6, lane = t & 63;
    int row = (bid & 2047) * 4 + w;
    const float* adj   = g ? adj2 : adj1;
    const float* edges = g ? edges2 : edges1;
    const float* We    = g ? We2 : We1;
    float* emsg  = ws + OFF_EMSG + (size_t)g * 524288;
    int*   cntg  = (int*)(ws + OFF_COUNT) + (size_t)g * 8192;
    int*   nz    = (int*)(ws + OFF_NZ)    + (size_t)g * 524288;
    float* aval  = ws + OFF_AVAL + (size_t)g * 524288;

    __shared__ int   lidx[4][64];
    __shared__ float lav[4][64];
    __shared__ float les[4][16];

    const float* arow = adj + (size_t)row * 128;
    float a0 = arow[lane], a1 = arow[64 + lane];
    unsigned long long m0 = __ballot(a0 != 0.f);
    unsigned long long m1 = __ballot(a1 != 0.f);
    int c0 = __popcll(m0);
    int cnt = c0 + __popcll(m1);
    unsigned long long below = ((unsigned long long)1 << lane) - 1ull;
    if (a0 != 0.f) { int pos = __popcll(m0 & below); if (pos < 64) { lidx[w][pos] = lane; lav[w][pos] = a0; } }
    if (a1 != 0.f) { int pos = c0 + __popcll(m1 & below); if (pos < 64) { lidx[w][pos] = lane + 64; lav[w][pos] = a1; } }
    int cc = cnt > 64 ? 64 : cnt;
    __syncthreads();

    nz[(size_t)row * 64 + lane]   = (lane < cc) ? lidx[w][lane] : 0;
    aval[(size_t)row * 64 + lane] = (lane < cc) ? lav[w][lane] : 0.f;

    int f = lane & 15, js = lane >> 4;
    float es = 0.f;
    const float* erow = edges + (size_t)row * 128 * 16;
    for (int j = js; j < cc; j += 4) es += lav[w][j] * erow[lidx[w][j] * 16 + f];
    es += __shfl_xor(es, 16);
    es += __shfl_xor(es, 32);
    if (lane < 16) les[w][lane] = es;
    __syncthreads();

    float acc = 0.f;
    #pragma unroll
    for (int ff = 0; ff < 16; ++ff) acc += les[w][ff] * We[ff * 64 + lane];
    emsg[(size_t)row * 64 + lane] = acc;
    if (lane == 0) cntg[row] = cc;
    return;
  }
  if (bid < 8228) {
    // ---------------- k6: embedding + LayerNorm + x@W_ih.T ----------------
    int bid6 = bid - 4096;
    int p = bid6 / 2066;
    int xb = bid6 % 2066;
    const int* ids = p ? ids2 : ids1;
    float* xw = ws + OFF_XW + (size_t)p * 2115584;
    __shared__ float wlds[1600];
    __shared__ float glds[50], blds[50], bs[32];
    __shared__ float xl6[8][52];
    for (int i = t; i < 1600; i += 256) wlds[i] = Wih[i];
    if (t < 50) { glds[t] = lng[t]; blds[t] = lnb[t]; }
    if (t < 32) bs[t] = bih[t] + bhh[t];
    __syncthreads();
    int grp = t >> 5, tl = t & 31;
    int newpos = (tl < 16) ? 2 * tl : 2 * tl - 31;
    const float L = 1.44269504088896f;
    float scale = (tl >= 16 && tl < 24) ? -2.f * L : -L;
    int q0 = xb * 32 + grp * 4;
    for (int qq = 0; qq < 4; ++qq) {
      int q = q0 + qq;                  // q = b*S + s, total exactly 64*1033
      int s = q % Ss;
      int id = ids[q];
      const float* wr = we + (size_t)id * 50;
      const float* pr = pe + (size_t)s * 50;
      float x1 = wr[tl] + pr[tl];
      bool has2 = (tl + 32) < 50;
      float x2 = has2 ? (wr[tl + 32] + pr[tl + 32]) : 0.f;
      float sm = x1 + x2, sq = x1 * x1 + x2 * x2;
      #pragma unroll
      for (int off = 16; off; off >>= 1) {
        sm += __shfl_xor(sm, off, 32);
        sq += __shfl_xor(sq, off, 32);
      }
      float u = sm * (1.f / 50.f);
      float var = fmaxf(sq * (1.f / 50.f) - u * u, 0.f);
      float rstd = rsqrtf(var + 1e-12f);
      xl6[grp][tl] = glds[tl] * (x1 - u) * rstd + blds[tl];
      if (has2) xl6[grp][tl + 32] = glds[tl + 32] * (x2 - u) * rstd + blds[tl + 32];
      __builtin_amdgcn_wave_barrier();
      float acc = bs[tl];
      #pragma unroll 10
      for (int k = 0; k < 50; ++k) acc += xl6[grp][k] * wlds[tl * 50 + k];
      xw[(size_t)q * 32 + newpos] = acc * scale;
      __builtin_amdgcn_wave_barrier();
    }
    return;
  }
  if (bid == 8228) {
    // ---- fold small matrices through W_final (reads inputs only) ----
    __shared__ float wf[468];
    for (int i = t; i < 468; i += 256) wf[i] = Wf[i];
    __syncthreads();
    float* w2f = ws + OFF_W2F;
    float* wmf = ws + OFF_WMF;
    float* wsf = ws + OFF_WSF;
    float* cst = ws + OFF_CONST;
    {
      float a1 = 0.f, a2 = 0.f;
      for (int k = 0; k < 45; ++k) {
        float v = W2[t * 45 + k];
        a1 += v * wf[128 + k];
        a2 += v * wf[346 + k];
      }
      w2f[t] = a1; w2f[256 + t] = a2;
    }
    if (t < 200) {
      float a1 = 0.f, a2 = 0.f;
      for (int k = 0; k < 45; ++k) {
        float v = Wm[t * 45 + k];
        a1 += v * wf[173 + k];
        a2 += v * wf[391 + k];
      }
      wmf[t] = a1; wmf[200 + t] = a2;
    }
    for (int i = t; i < 963; i += 256) {
      float a = 0.f;
      for (int k = 0; k < 32; ++k) a += Wsd[i * 32 + k] * wf[436 + k];
      wsf[i] = a;
    }
    if (t == 0) {
      float cc = bf[0];
      for (int k = 0; k < 45; ++k)
        cc += b2[k] * (wf[128 + k] + wf[346 + k]) + bm[k] * (wf[173 + k] + wf[391 + k]);
      for (int k = 0; k < 32; ++k) cc += bsd[k] * wf[436 + k];
      cst[0] = cc;
    }
    return;
  }
  // ---- zero blocks (8229..8244): pp accumulator ----
  int z = bid - 8229;                  // 0..15
  float* pp = ws + OFF_PPRE;
  f4 zz = {0.f, 0.f, 0.f, 0.f};
  size_t basei = (size_t)z * 2048 + (size_t)t * 8;
  *(f4*)&pp[basei] = zz;
  *(f4*)&pp[basei + 4] = zz;
}

// ================= kB: k_mpnn (blocks 0..127) + k7_lstm dual (128..143)
// k7: 2 independent chains per 16-lane group, MANUALLY interleaved at
// instruction granularity so B's ops fill A's exp2/rcp/DPP stalls.
__global__ __launch_bounds__(256) void kB(
    const float* __restrict__ nodes1, const float* __restrict__ nodes2,
    const float* __restrict__ Wm1, const float* __restrict__ Wm2,
    const float* __restrict__ Wup1, const float* __restrict__ Wup2,
    const float* __restrict__ bup1, const float* __restrict__ bup2,
    const float* __restrict__ Wr1, const float* __restrict__ Wr2,
    const float* __restrict__ br1, const float* __restrict__ br2,
    const float* __restrict__ Whh, float* __restrict__ ws) {
  __shared__ __attribute__((aligned(16))) float hl[8192];   // h (rows x 64)
  __shared__ __attribute__((aligned(16))) float xl[8192];   // hW -> msg -> nodes
  __shared__ __attribute__((aligned(16))) float wml[4096];  // W_msg; later reduce buf
  __shared__ __attribute__((aligned(16))) float wbl[8192];  // W_up; later W_read tile
  int bid = blockIdx.x;
  int t = threadIdx.x;
  if (bid >= 128) {
    // ---------------- k7: dual-chain LSTM, hand-interleaved ----------------
    if (t >= 64) return;
    int idx = bid - 128;                 // 0..15
    int p = idx >> 3, xb = idx & 7;
    const float* xw = ws + OFF_XW + (size_t)p * 2115584;
    float* hs = ws + OFF_HS + (size_t)p * HS_PSIZE;
    int lane16 = t & 15;
    int k = lane16 & 7;
    int half = lane16 >> 3;
    int bA = xb * 8 + (t >> 4);
    int bB = bA + 4;
    const float* xwA = xw + (size_t)bA * (Ss * 32) + lane16 * 2;
    const float* xwB = xw + (size_t)bB * (Ss * 32) + lane16 * 2;
    float* hqA = hs + (size_t)bA * HS_BSTRIDE + (size_t)k * HS_KSTRIDE;
    float* hqB = hs + (size_t)bB * HS_BSTRIDE + (size_t)k * HS_KSTRIDE;
    const float L = 1.44269504088896f;
    int ga = half ? 8 + k : k;          // f_k or i_k  (sigmoid)
    int gb = half ? 24 + k : 16 + k;    // o_k (sigmoid) or g_k (tanh)
    float sb_scale = half ? -L : -2.f * L;
    float wa[8], wb[8];
    #pragma unroll
    for (int r = 0; r < 8; ++r) {
      int j = (k - r) & 7;
      wa[r] = -L * Whh[ga * 8 + j];
      wb[r] = sb_scale * Whh[gb * 8 + j];
    }
    float cA_ = half ? 0.f : -4.f * L;  // x_own = fmaf(sa*cA_, tb, sa*cB_)
    float cB_ = half ? 1.f : 2.f * L;
    float hoA = 0.f, csA = 0.f, hoB = 0.f, csB = 0.f;
    float q0a = 0.f, q1a = 0.f, q2a = 0.f, q3a = 0.f;
    float q0b = 0.f, q1b = 0.f, q2b = 0.f, q3b = 0.f;

    f2 xA[8], xB[8];
    #pragma unroll
    for (int j = 0; j < 8; ++j) {
      xA[j] = *(const f2*)(xwA + (size_t)j * 32);
      xB[j] = *(const f2*)(xwB + (size_t)j * 32);
    }
    const float* pfA = xwA + 8 * 32;
    const float* pfB = xwB + 8 * 32;

    auto step2 = [&](f2 xcA, f2 xcB) {
      float hA1 = ROR16(hoA, 1); float hB1 = ROR16(hoB, 1);
      float hA2 = ROR16(hoA, 2); float hB2 = ROR16(hoB, 2);
      float hA3 = ROR16(hoA, 3); float hB3 = ROR16(hoB, 3);
      float hA4 = ROR16(hoA, 4); float hB4 = ROR16(hoB, 4);
      float hA5 = ROR16(hoA, 5); float hB5 = ROR16(hoB, 5);
      float hA6 = ROR16(hoA, 6); float hB6 = ROR16(hoB, 6);
      float hA7 = ROR16(hoA, 7); float hB7 = ROR16(hoB, 7);
      float aA0 = fmaf(hoA, wa[0], xcA.x); float aB0 = fmaf(hoB, wa[0], xcB.x);
      float bA0 = fmaf(hoA, wb[0], xcA.y); float bB0 = fmaf(hoB, wb[0], xcB.y);
      aA0 = fmaf(hA1, wa[1], aA0); aB0 = fmaf(hB1, wa[1], aB0);
      bA0 = fmaf(hA1, wb[1], bA0); bB0 = fmaf(hB1, wb[1], bB0);
      aA0 = fmaf(hA2, wa[2], aA0); aB0 = fmaf(hB2, wa[2], aB0);
      bA0 = fmaf(hA2, wb[2], bA0); bB0 = fmaf(hB2, wb[2], bB0);
      aA0 = fmaf(hA3, wa[3], aA0); aB0 = fmaf(hB3, wa[3], aB0);
      bA0 = fmaf(hA3, wb[3], bA0); bB0 = fmaf(hB3, wb[3], bB0);
      float aA1 = hA4 * wa[4]; float aB1 = hB4 * wa[4];
      float bA1 = hA4 * wb[4]; float bB1 = hB4 * wb[4];
      aA1 = fmaf(hA5, wa[5], aA1); aB1 = fmaf(hB5, wa[5], aB1);
      bA1 = fmaf(hA5, wb[5], bA1); bB1 = fmaf(hB5, wb[5], bB1);
      aA1 = fmaf(hA6, wa[6], aA1); aB1 = fmaf(hB6, wa[6], aB1);
      bA1 = fmaf(hA6, wb[6], bA1); bB1 = fmaf(hB6, wb[6], bB1);
      aA1 = fmaf(hA7, wa[7], aA1); aB1 = fmaf(hB7, wa[7], aB1);
      bA1 = fmaf(hA7, wb[7], bA1); bB1 = fmaf(hB7, wb[7], bB1);
      float accaA = aA0 + aA1; float accaB = aB0 + aB1;
      float accbA = bA0 + bA1; float accbB = bB0 + bB1;
      float eaA = __builtin_amdgcn_exp2f(accaA); float eaB = __builtin_amdgcn_exp2f(accaB);
      float ebA = __builtin_amdgcn_exp2f(accbA); float ebB = __builtin_amdgcn_exp2f(accbB);
      float saA = __builtin_amdgcn_rcpf(1.f + eaA); float saB = __builtin_amdgcn_rcpf(1.f + eaB);
      float tbA = __builtin_amdgcn_rcpf(1.f + ebA); float tbB = __builtin_amdgcn_rcpf(1.f + ebB);
      float xoA = fmaf(saA * cA_, tbA, saA * cB_); float xoB = fmaf(saB * cA_, tbB, saB * cB_);
      float xtA = ROR16(xoA, 8); float xtB = ROR16(xoB, 8);
      float ttA = ROR16(tbA, 8); float ttB = ROR16(tbB, 8);
      float FA = half ? xoA : xtA; float FB = half ? xoB : xtB;
      float PA = half ? xtA : xoA; float PB = half ? xtB : xoB;
      csA = fmaf(FA, csA, PA); csB = fmaf(FB, csB, PB);
      float e2A = __builtin_amdgcn_exp2f(csA); float e2B = __builtin_amdgcn_exp2f(csB);
      float tcA = __builtin_amdgcn_rcpf(1.f + e2A); float tcB = __builtin_amdgcn_rcpf(1.f + e2B);
      float soA = half ? tbA : ttA; float soB = half ? tbB : ttB;
      hoA = fmaf(soA + soA, tcA, -soA); hoB = fmaf(soB + soB, tcB, -soB);
    };

    for (int g = 0; g < 129; ++g) {                  // 129*8 = 1032 steps
      #pragma unroll
      for (int j = 0; j < 8; ++j) {
        f2 xcA = xA[j];
        xA[j] = *(const f2*)(pfA + j * 32);          // prefetch step s+8
        f2 xcB = xB[j];
        xB[j] = *(const f2*)(pfB + j * 32);
        step2(xcA, xcB);
        if (j == 0 || j == 4) { q0a = hoA; q0b = hoB; }
        else if (j == 1 || j == 5) { q1a = hoA; q1b = hoB; }
        else if (j == 2 || j == 6) { q2a = hoA; q2b = hoB; }
        else if (j == 3) {
          q3a = hoA; q3b = hoB;
          if (!half) { *(f4*)(hqA + 0) = (f4){q0a, q1a, q2a, q3a};
                       *(f4*)(hqB + 0) = (f4){q0b, q1b, q2b, q3b}; }
        } else {
          q3a = hoA; q3b = hoB;
          if (!half) { *(f4*)(hqA + 4) = (f4){q0a, q1a, q2a, q3a};
                       *(f4*)(hqB + 4) = (f4){q0b, q1b, q2b, q3b}; }
        }
      }
      pfA += 256; pfB += 256;
      hqA += 8; hqB += 8;
    }
    step2(xA[0], xB[0]);                             // final step s=1032
    if (!half) { hqA[0] = hoA; hqB[0] = hoB; }
    return;
  }
  // ---------------- k_mpnn: fused T=3 message passing + readout ----------
  int g = bid >> 6, b = bid & 63;
  const float* nodes = g ? nodes2 : nodes1;
  const float* Wm  = g ? Wm2 : Wm1;
  const float* Wup = g ? Wup2 : Wup1;
  const float* bup = g ? bup2 : bup1;
  const float* Wr  = g ? Wr2 : Wr1;
  const float* br  = g ? br2 : br1;
  const float* emsg = ws + OFF_EMSG + (size_t)g * 524288;
  const int*   cntg = (const int*)(ws + OFF_COUNT) + (size_t)g * 8192;
  const int*   nz   = (const int*)(ws + OFF_NZ) + (size_t)g * 524288;
  const float* aval = ws + OFF_AVAL + (size_t)g * 524288;
  float* out12 = ws + OFF_OUT12 + (size_t)g * 8192;

  int col4 = (t & 15) * 4, rg = t >> 4;
  int r0 = rg * 8;
  for (int i = t; i < 4096; i += 256) wml[i] = Wm[i];
  for (int i = t; i < 8192; i += 256) wbl[i] = Wup[i];
  for (int i = t; i < 8192; i += 256) hl[i] = nodes[(size_t)b * 8192 + i];
  __syncthreads();

  for (int it = 0; it < 3; ++it) {
    // ---- hW = h @ W_msg -> xl ----
    {
      f4 acc[8];
      #pragma unroll
      for (int rr = 0; rr < 8; ++rr) acc[rr] = (f4){0.f, 0.f, 0.f, 0.f};
      for (int f0 = 0; f0 < 64; f0 += 4) {
        f4 h4[8];
        #pragma unroll
        for (int rr = 0; rr < 8; ++rr) h4[rr] = *(const f4*)&hl[(r0 + rr) * 64 + f0];
        #pragma unroll
        for (int ff = 0; ff < 4; ++ff) {
          f4 w4 = *(const f4*)&wml[(f0 + ff) * 64 + col4];
          #pragma unroll
          for (int rr = 0; rr < 8; ++rr) acc[rr] += h4[rr][ff] * w4;
        }
      }
      #pragma unroll
      for (int rr = 0; rr < 8; ++rr) *(f4*)&xl[(r0 + rr) * 64 + col4] = acc[rr];
    }
    __syncthreads();
    // ---- msg gather (neighbors' hW from xl) into regs ----
    f4 msgv[8];
    #pragma unroll
    for (int rr = 0; rr < 8; ++rr) {
      int row = b * 128 + r0 + rr;
      f4 m = *(const f4*)&emsg[(size_t)row * 64 + col4];
      int cnt4 = (cntg[row] + 3) >> 2;
      const i4* nzr = (const i4*)(nz + (size_t)row * 64);
      const f4* avr = (const f4*)(aval + (size_t)row * 64);
      for (int j4 = 0; j4 < cnt4; ++j4) {
        i4 nq = nzr[j4];
        f4 aq = avr[j4];
        m += aq[0] * *(const f4*)&xl[nq[0] * 64 + col4];
        m += aq[1] * *(const f4*)&xl[nq[1] * 64 + col4];
        m += aq[2] * *(const f4*)&xl[nq[2] * 64 + col4];
        m += aq[3] * *(const f4*)&xl[nq[3] * 64 + col4];
      }
      msgv[rr] = m;
    }
    __syncthreads();
    #pragma unroll
    for (int rr = 0; rr < 8; ++rr) *(f4*)&xl[(r0 + rr) * 64 + col4] = msgv[rr];
    __syncthreads();
    // ---- upd = relu([h, msg] @ W_up + b_up), masked write to h ----
    {
      f4 u[8];
      #pragma unroll
      for (int rr = 0; rr < 8; ++rr) u[rr] = *(const f4*)&bup[col4];
      for (int f0 = 0; f0 < 64; f0 += 4) {
        f4 h4[8];
        #pragma unroll
        for (int rr = 0; rr < 8; ++rr) h4[rr] = *(const f4*)&hl[(r0 + rr) * 64 + f0];
        #pragma unroll
        for (int ff = 0; ff < 4; ++ff) {
          f4 w4 = *(const f4*)&wbl[(f0 + ff) * 64 + col4];
          #pragma unroll
          for (int rr = 0; rr < 8; ++rr) u[rr] += h4[rr][ff] * w4;
        }
      }
      for (int f0 = 0; f0 < 64; f0 += 4) {
        f4 m4[8];
        #pragma unroll
        for (int rr = 0; rr < 8; ++rr) m4[rr] = *(const f4*)&xl[(r0 + rr) * 64 + f0];
        #pragma unroll
        for (int ff = 0; ff < 4; ++ff) {
          f4 w4 = *(const f4*)&wbl[(64 + f0 + ff) * 64 + col4];
          #pragma unroll
          for (int rr = 0; rr < 8; ++rr) u[rr] += m4[rr][ff] * w4;
        }
      }
      __syncthreads();
      #pragma unroll
      for (int rr = 0; rr < 8; ++rr) {
        int row = b * 128 + r0 + rr;
        if (cntg[row] > 0) *(f4*)&hl[(r0 + rr) * 64 + col4] = relu4(u[rr]);
      }
    }
    __syncthreads();
  }

  // ---- readout: r = relu([h, nodes] @ W_read + b_read); masked row-sum ----
  for (int i = t; i < 8192; i += 256) xl[i] = nodes[(size_t)b * 8192 + i];
  __syncthreads();
  for (int kt = 0; kt < 2; ++kt) {
    for (int i = t; i < 8192; i += 256) {
      int f = i >> 6, c = i & 63;
      wbl[i] = Wr[f * 128 + kt * 64 + c];
    }
    __syncthreads();
    f4 part = {0.f, 0.f, 0.f, 0.f};
    {
      f4 u[8];
      #pragma unroll
      for (int rr = 0; rr < 8; ++rr) u[rr] = *(const f4*)&br[kt * 64 + col4];
      for (int f0 = 0; f0 < 64; f0 += 4) {
        f4 h4[8];
        #pragma unroll
        for (int rr = 0; rr < 8; ++rr) h4[rr] = *(const f4*)&hl[(r0 + rr) * 64 + f0];
        #pragma unroll
        for (int ff = 0; ff < 4; ++ff) {
          f4 w4 = *(const f4*)&wbl[(f0 + ff) * 64 + col4];
          #pragma unroll
          for (int rr = 0; rr < 8; ++rr) u[rr] += h4[rr][ff] * w4;
        }
      }
      for (int f0 = 0; f0 < 64; f0 += 4) {
        f4 n4[8];
        #pragma unroll
        for (int rr = 0; rr < 8; ++rr) n4[rr] = *(const f4*)&xl[(r0 + rr) * 64 + f0];
        #pragma unroll
        for (int ff = 0; ff < 4; ++ff) {
          f4 w4 = *(const f4*)&wbl[(64 + f0 + ff) * 64 + col4];
          #pragma unroll
          for (int rr = 0; rr < 8; ++rr) u[rr] += n4[rr][ff] * w4;
        }
      }
      #pragma unroll
      for (int rr = 0; rr < 8; ++rr) {
        int row = b * 128 + r0 + rr;
        if (cntg[row] > 0) part += relu4(u[rr]);
      }
    }
    *(f4*)&wml[rg * 64 + col4] = part;
    __syncthreads();
    for (int off = 8; off; off >>= 1) {
      if (rg < off) {
        f4 v = *(f4*)&wml[rg * 64 + col4] + *(f4*)&wml[(rg + off) * 64 + col4];
        *(f4*)&wml[rg * 64 + col4] = v;
      }
      __syncthreads();
    }
    if (rg == 0) *(f4*)&out12[(size_t)b * 128 + kt * 64 + col4] = *(f4*)&wml[col4];
    __syncthreads();
  }
}

// ================= kC: k8_dec (256 blocks) ---------------------------------
__global__ __launch_bounds__(256) void kC(
    const float* __restrict__ W1, float* __restrict__ ws) {
  int bid = blockIdx.x;
  int t = threadIdx.x;
  int ks = bid & 31, jt = (bid >> 5) & 3, p = bid >> 7;
  const float* hs = ws + OFF_HS + (size_t)p * HS_PSIZE;
  float* pp = ws + OFF_PPRE + (size_t)p * 16384;
  int s0 = ks * 32;
  int s1 = (ks == 31) ? Ss : s0 + 32;   // last chunk: 41 s (f4 groups + pad)
  int j0 = jt * 64;
  __shared__ __attribute__((aligned(16))) float hsl[4][768];  // [s][b*12+k]
  __shared__ __attribute__((aligned(16))) float w1l[4][512];  // [s][l*64+j]
  int jl = (t & 15) * 4, bb = t >> 4;   // group bb: b in {bb, bb+16, bb+32, bb+48}
  f4 acc[4] = {};
  for (int sb = s0; sb < s1; sb += 4) {
    #pragma unroll
    for (int u = 0; u < 2; ++u) {
      int bk = t + 256 * u;
      int b = bk >> 3, k = bk & 7;
      f4 v = *(const f4*)&hs[(size_t)b * HS_BSTRIDE + (size_t)k * HS_KSTRIDE + sb];
      int c = b * 12 + k;
      hsl[0][c] = v[0]; hsl[1][c] = v[1]; hsl[2][c] = v[2]; hsl[3][c] = v[3];
    }
    #pragma unroll
    for (int u = 0; u < 2; ++u) {
      int idx = t + 256 * u;
      int ss = idx >> 7, l = (idx >> 4) & 7, jj = (idx & 15) * 4;
      int s = sb + ss;
      f4 wv = (s < Ss) ? *(const f4*)&W1[(size_t)(s * 8 + l) * 256 + j0 + jj]
                       : (f4){0.f, 0.f, 0.f, 0.f};
      *(f4*)&w1l[ss][l * 64 + jj] = wv;
    }
    __syncthreads();
    #pragma unroll
    for (int ss = 0; ss < 4; ++ss) {
      f4 r[4][2];
      #pragma unroll
      for (int i = 0; i < 4; ++i) {
        int b = bb + 16 * i;
        r[i][0] = *(const f4*)&hsl[ss][b * 12];
        r[i][1] = *(const f4*)&hsl[ss][b * 12 + 4];
      }
      #pragma unroll
      for (int l = 0; l < 8; ++l) {
        f4 wv = *(const f4*)&w1l[ss][l * 64 + jl];
        #pragma unroll
        for (int i = 0; i < 4; ++i) {
          float hv = (l < 4) ? r[i][0][l] : r[i][1][l - 4];
          acc[i] += hv * wv;
        }
      }
    }
    __syncthreads();
  }
  #pragma unroll
  for (int i = 0; i < 4; ++i) {
    int b = bb + 16 * i;
    float* dst = pp + (size_t)b * 256 + j0 + jl;
    atomicAdd(dst + 0, acc[i][0]); atomicAdd(dst + 1, acc[i][1]);
    atomicAdd(dst + 2, acc[i][2]); atomicAdd(dst + 3, acc[i][3]);
  }
}

// ================= kD: k_final with inline BatchNorm ------------------------
__global__ __launch_bounds__(256) void kD(
    const float* __restrict__ b1, const float* __restrict__ bng,
    const float* __restrict__ bnb,
    const float* __restrict__ d1m, const float* __restrict__ d2m,
    const float* __restrict__ se, const float* __restrict__ Wf,
    float* __restrict__ ws, float* __restrict__ out) {
  int b = blockIdx.x, t = threadIdx.x;
  const float* out12 = ws + OFF_OUT12;
  const float* pp0 = ws + OFF_PPRE;
  const float* pp1 = ws + OFF_PPRE + 16384;
  const float* w2f = ws + OFF_W2F;
  const float* wmf = ws + OFF_WMF;
  const float* wsf = ws + OFF_WSF;
  float bj = b1[t];
  float sm0 = 0.f, sq0 = 0.f, sm1 = 0.f, sq1 = 0.f;
  for (int bb = 0; bb < 64; ++bb) {
    float v0 = fmaxf(pp0[bb * 256 + t] + bj, 0.f);
    float v1 = fmaxf(pp1[bb * 256 + t] + bj, 0.f);
    sm0 += v0; sq0 += v0 * v0;
    sm1 += v1; sq1 += v1 * v1;
  }
  float m0 = sm0 * (1.f / 64.f);
  float var0 = fmaxf(sq0 * (1.f / 64.f) - m0 * m0, 0.f);
  float rstd0 = rsqrtf(var0 + 1e-5f);
  float sc0 = bng[t] * rstd0, sh0 = bnb[t] - m0 * sc0;
  float m1 = sm1 * (1.f / 64.f);
  float var1 = fmaxf(sq1 * (1.f / 64.f) - m1 * m1, 0.f);
  float rstd1 = rsqrtf(var1 + 1e-5f);
  float sc1 = bng[t] * rstd1, sh1 = bnb[t] - m1 * sc1;
  float val0 = sc0 * fmaxf(pp0[b * 256 + t] + bj, 0.f) + sh0;
  float val1 = sc1 * fmaxf(pp1[b * 256 + t] + bj, 0.f) + sh1;
  float acc = val0 * w2f[t] + val1 * w2f[256 + t];
  if (t < 128) {
    acc += out12[b * 128 + t] * Wf[t];
    acc += out12[8192 + b * 128 + t] * Wf[218 + t];
  }
  if (t < 200) {
    acc += d1m[b * 200 + t] * wmf[t];
    acc += d2m[b * 200 + t] * wmf[200 + t];
  }
  for (int i = t; i < 963; i += 256) acc += se[b * 963 + i] * wsf[i];
  __shared__ float red[256];
  red[t] = acc;
  __syncthreads();
  for (int off = 128; off; off >>= 1) {
    if (t < off) red[t] += red[t + off];
    __syncthreads();
  }
  if (t == 0) out[b] = red[0] + (ws + OFF_CONST)[0];
}

extern "C" void kernel_launch(void* const* d_in, const int* in_sizes, int n_in,
                              void* d_out, int out_size, void* d_ws, size_t ws_size,
                              hipStream_t stream) {
  const float* adj1  = (const float*)d_in[0];
  const float* nodes1= (const float*)d_in[1];
  const float* edges1= (const float*)d_in[2];
  const float* adj2  = (const float*)d_in[3];
  const float* nodes2= (const float*)d_in[4];
  const float* edges2= (const float*)d_in[5];
  const float* d1m   = (const float*)d_in[6];
  const float* d2m   = (const float*)d_in[7];
  const int*   ids1  = (const int*)d_in[8];
  const int*   ids2  = (const int*)d_in[9];
  const float* se    = (const float*)d_in[10];
  const float* we    = (const float*)d_in[11];
  const float* pe    = (const float*)d_in[12];
  const float* lng   = (const float*)d_in[13];
  const float* lnb   = (const float*)d_in[14];
  const float* Wih   = (const float*)d_in[15];
  const float* Whh   = (const float*)d_in[16];
  const float* bih   = (const float*)d_in[17];
  const float* bhh   = (const float*)d_in[18];
  const float* W1    = (const float*)d_in[19];
  const float* b1    = (const float*)d_in[20];
  const float* bng   = (const float*)d_in[21];
  const float* bnb   = (const float*)d_in[22];
  const float* W2    = (const float*)d_in[23];
  const float* b2    = (const float*)d_in[24];
  const float* Wm1   = (const float*)d_in[25];
  const float* We1   = (const float*)d_in[26];
  const float* Wup1  = (const float*)d_in[27];
  const float* bup1  = (const float*)d_in[28];
  const float* Wr1   = (const float*)d_in[29];
  const float* br1   = (const float*)d_in[30];
  const float* Wm2   = (const float*)d_in[31];
  const float* We2   = (const float*)d_in[32];
  const float* Wup2  = (const float*)d_in[33];
  const float* bup2  = (const float*)d_in[34];
  const float* Wr2   = (const float*)d_in[35];
  const float* br2   = (const float*)d_in[36];
  const float* Wmo   = (const float*)d_in[37];
  const float* bmo   = (const float*)d_in[38];
  const float* Wsd   = (const float*)d_in[39];
  const float* bsd   = (const float*)d_in[40];
  const float* Wf    = (const float*)d_in[41];
  const float* bf    = (const float*)d_in[42];
  float* ws = (float*)d_ws;
  float* out = (float*)d_out;

  // A: adjacency prep + protein front-end + W_final fold + zero(pp)
  kA<<<8245, 256, 0, stream>>>(adj1, adj2, edges1, edges2, We1, We2,
                               ids1, ids2, we, pe, lng, lnb, Wih, bih, bhh,
                               W2, b2, Wmo, bmo, Wsd, bsd, Wf, bf, ws);
  // B: fused MPNN (128 blocks) + hand-interleaved dual-chain LSTM (16 blocks)
  kB<<<144, 256, 0, stream>>>(nodes1, nodes2, Wm1, Wm2, Wup1, Wup2, bup1, bup2,
                              Wr1, Wr2, br1, br2, Whh, ws);
  // C: dec_W1 split-K GEMM (256 blocks)
  kC<<<256, 256, 0, stream>>>(W1, ws);
  // D: final dot with inline BatchNorm
  kD<<<64, 256, 0, stream>>>(b1, bng, bnb, d1m, d2m, se, Wf, ws, out);
}

// Round 14
// 223.779 us; speedup vs baseline: 1.3584x; 1.3584x over previous
//
#include <hip/hip_runtime.h>
#include <hip/hip_bf16.h>
#include <math.h>

#define Bb 64
#define Nn 128
#define FNf 64
#define Ss 1033
#define EMBe 50

typedef float f4 __attribute__((ext_vector_type(4)));
typedef float f2 __attribute__((ext_vector_type(2)));
typedef int   i4 __attribute__((ext_vector_type(4)));

// hs layout: [b][k][s] with padded strides for 16B-aligned f4 stores
#define HS_KSTRIDE 1036
#define HS_BSTRIDE 8288   // 8*1036
#define HS_PSIZE   530432 // 64*8288

// ---- workspace offsets (in floats) ----
constexpr size_t OFF_EMSG  = 2*524288 + 2*524288;       // 2 * 524288  (edge_msg)
constexpr size_t OFF_MASK  = OFF_EMSG  + 2*524288;      // (unused)
constexpr size_t OFF_OUT12 = OFF_MASK  + 2*8192;        // 2 * 8192    (graph readouts)
constexpr size_t OFF_PPRE  = OFF_OUT12 + 2*8192;        // 2 * 16384   (dec1 pre-act accum)
constexpr size_t OFF_PBN   = OFF_PPRE  + 2*16384;       // (unused)
constexpr size_t OFF_XW    = OFF_PBN   + 2*16384;       // 2 * 2115584 (log2e-scaled x@W_ih.T + biases, permuted)
constexpr size_t OFF_HS    = OFF_XW    + 2*2115584;     // 2 * HS_PSIZE (LSTM hidden seq, [b][k][s])
constexpr size_t OFF_W2F   = OFF_HS    + 2*HS_PSIZE;    // 2 * 256
constexpr size_t OFF_WMF   = OFF_W2F   + 2*256;         // 2 * 200
constexpr size_t OFF_WSF   = OFF_WMF   + 2*200;         // 963
constexpr size_t OFF_CONST = OFF_WSF   + 964;           // 4
constexpr size_t OFF_COUNT = OFF_CONST + 4;             // 2 * 8192 (int)
constexpr size_t OFF_NZ    = OFF_COUNT + 2*8192;        // 2 * 524288 (int, zero-padded per row)
constexpr size_t OFF_AVAL  = OFF_NZ    + 2*524288;      // 2 * 524288 (zero-padded per row)

__device__ inline f4 relu4(f4 v) {
  v[0] = fmaxf(v[0], 0.f); v[1] = fmaxf(v[1], 0.f);
  v[2] = fmaxf(v[2], 0.f); v[3] = fmaxf(v[3], 0.f);
  return v;
}

// DPP row rotate-right: dst[i] = src[(i - n) & 15] within each 16-lane row.
#define ROR16(x, n) __int_as_float(__builtin_amdgcn_update_dpp(0, __float_as_int(x), 0x120 + (n), 0xF, 0xF, true))

// ================= kA: k1 (0..4095) + k6 (4096..8227) + fold (8228) + zero (8229..8244)
__global__ __launch_bounds__(256) void kA(
    const float* __restrict__ adj1, const float* __restrict__ adj2,
    const float* __restrict__ edges1, const float* __restrict__ edges2,
    const float* __restrict__ We1, const float* __restrict__ We2,
    const int* __restrict__ ids1, const int* __restrict__ ids2,
    const float* __restrict__ we, const float* __restrict__ pe,
    const float* __restrict__ lng, const float* __restrict__ lnb,
    const float* __restrict__ Wih, const float* __restrict__ bih,
    const float* __restrict__ bhh,
    const float* __restrict__ W2, const float* __restrict__ b2,
    const float* __restrict__ Wm, const float* __restrict__ bm,
    const float* __restrict__ Wsd, const float* __restrict__ bsd,
    const float* __restrict__ Wf, const float* __restrict__ bf,
    float* __restrict__ ws) {
  int bid = blockIdx.x;
  int t = threadIdx.x;
  if (bid < 4096) {
    // ---------------- k1: adjacency compaction + edge_msg ----------------
    int g = bid >> 11;
    int w = t >> 6, lane = t & 63;
    int row = (bid & 2047) * 4 + w;
    const float* adj   = g ? adj2 : adj1;
    const float* edges = g ? edges2 : edges1;
    const float* We    = g ? We2 : We1;
    float* emsg  = ws + OFF_EMSG + (size_t)g * 524288;
    int*   cntg  = (int*)(ws + OFF_COUNT) + (size_t)g * 8192;
    int*   nz    = (int*)(ws + OFF_NZ)    + (size_t)g * 524288;
    float* aval  = ws + OFF_AVAL + (size_t)g * 524288;

    __shared__ int   lidx[4][64];
    __shared__ float lav[4][64];
    __shared__ float les[4][16];

    const float* arow = adj + (size_t)row * 128;
    float a0 = arow[lane], a1 = arow[64 + lane];
    unsigned long long m0 = __ballot(a0 != 0.f);
    unsigned long long m1 = __ballot(a1 != 0.f);
    int c0 = __popcll(m0);
    int cnt = c0 + __popcll(m1);
    unsigned long long below = ((unsigned long long)1 << lane) - 1ull;
    if (a0 != 0.f) { int pos = __popcll(m0 & below); if (pos < 64) { lidx[w][pos] = lane; lav[w][pos] = a0; } }
    if (a1 != 0.f) { int pos = c0 + __popcll(m1 & below); if (pos < 64) { lidx[w][pos] = lane + 64; lav[w][pos] = a1; } }
    int cc = cnt > 64 ? 64 : cnt;
    __syncthreads();

    nz[(size_t)row * 64 + lane]   = (lane < cc) ? lidx[w][lane] : 0;
    aval[(size_t)row * 64 + lane] = (lane < cc) ? lav[w][lane] : 0.f;

    int f = lane & 15, js = lane >> 4;
    float es = 0.f;
    const float* erow = edges + (size_t)row * 128 * 16;
    for (int j = js; j < cc; j += 4) es += lav[w][j] * erow[lidx[w][j] * 16 + f];
    es += __shfl_xor(es, 16);
    es += __shfl_xor(es, 32);
    if (lane < 16) les[w][lane] = es;
    __syncthreads();

    float acc = 0.f;
    #pragma unroll
    for (int ff = 0; ff < 16; ++ff) acc += les[w][ff] * We[ff * 64 + lane];
    emsg[(size_t)row * 64 + lane] = acc;
    if (lane == 0) cntg[row] = cc;
    return;
  }
  if (bid < 8228) {
    // ---------------- k6: embedding + LayerNorm + x@W_ih.T ----------------
    int bid6 = bid - 4096;
    int p = bid6 / 2066;
    int xb = bid6 % 2066;
    const int* ids = p ? ids2 : ids1;
    float* xw = ws + OFF_XW + (size_t)p * 2115584;
    __shared__ float wlds[1600];
    __shared__ float glds[50], blds[50], bs[32];
    __shared__ float xl6[8][52];
    for (int i = t; i < 1600; i += 256) wlds[i] = Wih[i];
    if (t < 50) { glds[t] = lng[t]; blds[t] = lnb[t]; }
    if (t < 32) bs[t] = bih[t] + bhh[t];
    __syncthreads();
    int grp = t >> 5, tl = t & 31;
    int newpos = (tl < 16) ? 2 * tl : 2 * tl - 31;
    const float L = 1.44269504088896f;
    float scale = (tl >= 16 && tl < 24) ? -2.f * L : -L;
    int q0 = xb * 32 + grp * 4;
    for (int qq = 0; qq < 4; ++qq) {
      int q = q0 + qq;                  // q = b*S + s, total exactly 64*1033
      int s = q % Ss;
      int id = ids[q];
      const float* wr = we + (size_t)id * 50;
      const float* pr = pe + (size_t)s * 50;
      float x1 = wr[tl] + pr[tl];
      bool has2 = (tl + 32) < 50;
      float x2 = has2 ? (wr[tl + 32] + pr[tl + 32]) : 0.f;
      float sm = x1 + x2, sq = x1 * x1 + x2 * x2;
      #pragma unroll
      for (int off = 16; off; off >>= 1) {
        sm += __shfl_xor(sm, off, 32);
        sq += __shfl_xor(sq, off, 32);
      }
      float u = sm * (1.f / 50.f);
      float var = fmaxf(sq * (1.f / 50.f) - u * u, 0.f);
      float rstd = rsqrtf(var + 1e-12f);
      xl6[grp][tl] = glds[tl] * (x1 - u) * rstd + blds[tl];
      if (has2) xl6[grp][tl + 32] = glds[tl + 32] * (x2 - u) * rstd + blds[tl + 32];
      __builtin_amdgcn_wave_barrier();
      float acc = bs[tl];
      #pragma unroll 10
      for (int k = 0; k < 50; ++k) acc += xl6[grp][k] * wlds[tl * 50 + k];
      xw[(size_t)q * 32 + newpos] = acc * scale;
      __builtin_amdgcn_wave_barrier();
    }
    return;
  }
  if (bid == 8228) {
    // ---- fold small matrices through W_final (reads inputs only) ----
    __shared__ float wf[468];
    for (int i = t; i < 468; i += 256) wf[i] = Wf[i];
    __syncthreads();
    float* w2f = ws + OFF_W2F;
    float* wmf = ws + OFF_WMF;
    float* wsf = ws + OFF_WSF;
    float* cst = ws + OFF_CONST;
    {
      float a1 = 0.f, a2 = 0.f;
      for (int k = 0; k < 45; ++k) {
        float v = W2[t * 45 + k];
        a1 += v * wf[128 + k];
        a2 += v * wf[346 + k];
      }
      w2f[t] = a1; w2f[256 + t] = a2;
    }
    if (t < 200) {
      float a1 = 0.f, a2 = 0.f;
      for (int k = 0; k < 45; ++k) {
        float v = Wm[t * 45 + k];
        a1 += v * wf[173 + k];
        a2 += v * wf[391 + k];
      }
      wmf[t] = a1; wmf[200 + t] = a2;
    }
    for (int i = t; i < 963; i += 256) {
      float a = 0.f;
      for (int k = 0; k < 32; ++k) a += Wsd[i * 32 + k] * wf[436 + k];
      wsf[i] = a;
    }
    if (t == 0) {
      float cc = bf[0];
      for (int k = 0; k < 45; ++k)
        cc += b2[k] * (wf[128 + k] + wf[346 + k]) + bm[k] * (wf[173 + k] + wf[391 + k]);
      for (int k = 0; k < 32; ++k) cc += bsd[k] * wf[436 + k];
      cst[0] = cc;
    }
    return;
  }
  // ---- zero blocks (8229..8244): pp accumulator ----
  int z = bid - 8229;                  // 0..15
  float* pp = ws + OFF_PPRE;
  f4 zz = {0.f, 0.f, 0.f, 0.f};
  size_t basei = (size_t)z * 2048 + (size_t)t * 8;
  *(f4*)&pp[basei] = zz;
  *(f4*)&pp[basei + 4] = zz;
}

// ================= kB: k_mpnn (blocks 0..127) + k7_lstm (blocks 128..159)
__global__ __launch_bounds__(256) void kB(
    const float* __restrict__ nodes1, const float* __restrict__ nodes2,
    const float* __restrict__ Wm1, const float* __restrict__ Wm2,
    const float* __restrict__ Wup1, const float* __restrict__ Wup2,
    const float* __restrict__ bup1, const float* __restrict__ bup2,
    const float* __restrict__ Wr1, const float* __restrict__ Wr2,
    const float* __restrict__ br1, const float* __restrict__ br2,
    const float* __restrict__ Whh, float* __restrict__ ws) {
  __shared__ __attribute__((aligned(16))) float hl[8192];   // h (rows x 64)
  __shared__ __attribute__((aligned(16))) float xl[8192];   // hW -> msg -> nodes
  __shared__ __attribute__((aligned(16))) float wml[4096];  // W_msg; later reduce buf
  __shared__ __attribute__((aligned(16))) float wbl[8192];  // W_up; later W_read tile
  int bid = blockIdx.x;
  int t = threadIdx.x;
  if (bid >= 128) {
    // ---------------- k7: sequential LSTM scan (1 wave active) ------------
    if (t >= 64) return;
    int idx = bid - 128;
    int p = idx >> 4, xb = idx & 15;
    const float* xw = ws + OFF_XW + (size_t)p * 2115584;
    float* hs = ws + OFF_HS + (size_t)p * HS_PSIZE;
    int lane16 = t & 15;
    int k = lane16 & 7;
    int half = lane16 >> 3;
    int b = xb * 4 + (t >> 4);
    const float* xwp = xw + (size_t)b * (Ss * 32) + lane16 * 2;
    float* hq = hs + (size_t)b * HS_BSTRIDE + (size_t)k * HS_KSTRIDE;  // [b][k][s]
    const float L = 1.44269504088896f;
    int ga = half ? 8 + k : k;          // f_k or i_k  (sigmoid)
    int gb = half ? 24 + k : 16 + k;    // o_k (sigmoid) or g_k (tanh)
    float sb_scale = half ? -L : -2.f * L;
    float wa[8], wb[8];
    #pragma unroll
    for (int r = 0; r < 8; ++r) {
      int j = (k - r) & 7;
      wa[r] = -L * Whh[ga * 8 + j];
      wb[r] = sb_scale * Whh[gb * 8 + j];
    }
    float A = half ? 0.f : -4.f * L;    // x_own = fmaf(sa*A, tb, sa*B)
    float B = half ? 1.f : 2.f * L;
    float ho = 0.f, cs = 0.f;
    float q0v = 0.f, q1v = 0.f, q2v = 0.f, q3v = 0.f;

    f2 x[8];
    #pragma unroll
    for (int j = 0; j < 8; ++j) x[j] = *(const f2*)(xwp + (size_t)j * 32);
    const float* pf = xwp + 8 * 32;

    auto step = [&](f2 xc) {
      float h1 = ROR16(ho, 1);
      float h2 = ROR16(ho, 2);
      float h3 = ROR16(ho, 3);
      float h4 = ROR16(ho, 4);
      float h5 = ROR16(ho, 5);
      float h6 = ROR16(ho, 6);
      float h7 = ROR16(ho, 7);
      float a0 = fmaf(ho, wa[0], xc.x);
      float b0 = fmaf(ho, wb[0], xc.y);
      a0 = fmaf(h1, wa[1], a0);  b0 = fmaf(h1, wb[1], b0);
      a0 = fmaf(h2, wa[2], a0);  b0 = fmaf(h2, wb[2], b0);
      a0 = fmaf(h3, wa[3], a0);  b0 = fmaf(h3, wb[3], b0);
      float a1 = h4 * wa[4];     float b1 = h4 * wb[4];
      a1 = fmaf(h5, wa[5], a1);  b1 = fmaf(h5, wb[5], b1);
      a1 = fmaf(h6, wa[6], a1);  b1 = fmaf(h6, wb[6], b1);
      a1 = fmaf(h7, wa[7], a1);  b1 = fmaf(h7, wb[7], b1);
      float acc_a = a0 + a1;
      float acc_b = b0 + b1;
      float ea = __builtin_amdgcn_exp2f(acc_a);
      float sa = __builtin_amdgcn_rcpf(1.f + ea);   // sigmoid(i or f)
      float eb = __builtin_amdgcn_exp2f(acc_b);
      float tb = __builtin_amdgcn_rcpf(1.f + eb);   // (tanh(g)+1)/2 or sigmoid(o)
      float x_own = fmaf(sa * A, tb, sa * B);
      float x_oth = ROR16(x_own, 8);
      float t_oth = ROR16(tb, 8);
      float F  = half ? x_own : x_oth;
      float P2 = half ? x_oth : x_own;
      cs = fmaf(F, cs, P2);                          // cs = -2*log2e*c
      float e2 = __builtin_amdgcn_exp2f(cs);
      float tc = __builtin_amdgcn_rcpf(1.f + e2);    // (tanh(c)+1)/2
      float so = half ? tb : t_oth;                  // sigma(o)
      ho = fmaf(so + so, tc, -so);                   // so * tanh(c)
    };

    for (int g = 0; g < 129; ++g) {                  // 129*8 = 1032 steps
      #pragma unroll
      for (int j = 0; j < 8; ++j) {
        f2 xc = x[j];
        x[j] = *(const f2*)(pf + j * 32);            // prefetch step s+8
        step(xc);
        if (j == 0 || j == 4) q0v = ho;
        else if (j == 1 || j == 5) q1v = ho;
        else if (j == 2 || j == 6) q2v = ho;
        else if (j == 3) { q3v = ho; if (!half) *(f4*)(hq + 0) = (f4){q0v, q1v, q2v, q3v}; }
        else { q3v = ho; if (!half) *(f4*)(hq + 4) = (f4){q0v, q1v, q2v, q3v}; }
      }
      pf += 256;
      hq += 8;
    }
    step(x[0]);                                      // final step s=1032
    if (!half) hq[0] = ho;
    return;
  }
  // ---------------- k_mpnn: fused T=3 message passing + readout ----------
  int g = bid >> 6, b = bid & 63;
  const float* nodes = g ? nodes2 : nodes1;
  const float* Wm  = g ? Wm2 : Wm1;
  const float* Wup = g ? Wup2 : Wup1;
  const float* bup = g ? bup2 : bup1;
  const float* Wr  = g ? Wr2 : Wr1;
  const float* br  = g ? br2 : br1;
  const float* emsg = ws + OFF_EMSG + (size_t)g * 524288;
  const int*   cntg = (const int*)(ws + OFF_COUNT) + (size_t)g * 8192;
  const int*   nz   = (const int*)(ws + OFF_NZ) + (size_t)g * 524288;
  const float* aval = ws + OFF_AVAL + (size_t)g * 524288;
  float* out12 = ws + OFF_OUT12 + (size_t)g * 8192;

  int col4 = (t & 15) * 4, rg = t >> 4;
  int r0 = rg * 8;
  for (int i = t; i < 4096; i += 256) wml[i] = Wm[i];
  for (int i = t; i < 8192; i += 256) wbl[i] = Wup[i];
  for (int i = t; i < 8192; i += 256) hl[i] = nodes[(size_t)b * 8192 + i];
  __syncthreads();

  for (int it = 0; it < 3; ++it) {
    // ---- hW = h @ W_msg -> xl ----
    {
      f4 acc[8];
      #pragma unroll
      for (int rr = 0; rr < 8; ++rr) acc[rr] = (f4){0.f, 0.f, 0.f, 0.f};
      for (int f0 = 0; f0 < 64; f0 += 4) {
        f4 h4[8];
        #pragma unroll
        for (int rr = 0; rr < 8; ++rr) h4[rr] = *(const f4*)&hl[(r0 + rr) * 64 + f0];
        #pragma unroll
        for (int ff = 0; ff < 4; ++ff) {
          f4 w4 = *(const f4*)&wml[(f0 + ff) * 64 + col4];
          #pragma unroll
          for (int rr = 0; rr < 8; ++rr) acc[rr] += h4[rr][ff] * w4;
        }
      }
      #pragma unroll
      for (int rr = 0; rr < 8; ++rr) *(f4*)&xl[(r0 + rr) * 64 + col4] = acc[rr];
    }
    __syncthreads();
    // ---- msg gather (neighbors' hW from xl) into regs ----
    f4 msgv[8];
    #pragma unroll
    for (int rr = 0; rr < 8; ++rr) {
      int row = b * 128 + r0 + rr;
      f4 m = *(const f4*)&emsg[(size_t)row * 64 + col4];
      int cnt4 = (cntg[row] + 3) >> 2;
      const i4* nzr = (const i4*)(nz + (size_t)row * 64);
      const f4* avr = (const f4*)(aval + (size_t)row * 64);
      for (int j4 = 0; j4 < cnt4; ++j4) {
        i4 nq = nzr[j4];
        f4 aq = avr[j4];
        m += aq[0] * *(const f4*)&xl[nq[0] * 64 + col4];
        m += aq[1] * *(const f4*)&xl[nq[1] * 64 + col4];
        m += aq[2] * *(const f4*)&xl[nq[2] * 64 + col4];
        m += aq[3] * *(const f4*)&xl[nq[3] * 64 + col4];
      }
      msgv[rr] = m;
    }
    __syncthreads();
    #pragma unroll
    for (int rr = 0; rr < 8; ++rr) *(f4*)&xl[(r0 + rr) * 64 + col4] = msgv[rr];
    __syncthreads();
    // ---- upd = relu([h, msg] @ W_up + b_up), masked write to h ----
    {
      f4 u[8];
      #pragma unroll
      for (int rr = 0; rr < 8; ++rr) u[rr] = *(const f4*)&bup[col4];
      for (int f0 = 0; f0 < 64; f0 += 4) {
        f4 h4[8];
        #pragma unroll
        for (int rr = 0; rr < 8; ++rr) h4[rr] = *(const f4*)&hl[(r0 + rr) * 64 + f0];
        #pragma unroll
        for (int ff = 0; ff < 4; ++ff) {
          f4 w4 = *(const f4*)&wbl[(f0 + ff) * 64 + col4];
          #pragma unroll
          for (int rr = 0; rr < 8; ++rr) u[rr] += h4[rr][ff] * w4;
        }
      }
      for (int f0 = 0; f0 < 64; f0 += 4) {
        f4 m4[8];
        #pragma unroll
        for (int rr = 0; rr < 8; ++rr) m4[rr] = *(const f4*)&xl[(r0 + rr) * 64 + f0];
        #pragma unroll
        for (int ff = 0; ff < 4; ++ff) {
          f4 w4 = *(const f4*)&wbl[(64 + f0 + ff) * 64 + col4];
          #pragma unroll
          for (int rr = 0; rr < 8; ++rr) u[rr] += m4[rr][ff] * w4;
        }
      }
      __syncthreads();
      #pragma unroll
      for (int rr = 0; rr < 8; ++rr) {
        int row = b * 128 + r0 + rr;
        if (cntg[row] > 0) *(f4*)&hl[(r0 + rr) * 64 + col4] = relu4(u[rr]);
      }
    }
    __syncthreads();
  }

  // ---- readout: r = relu([h, nodes] @ W_read + b_read); masked row-sum ----
  for (int i = t; i < 8192; i += 256) xl[i] = nodes[(size_t)b * 8192 + i];
  __syncthreads();
  for (int kt = 0; kt < 2; ++kt) {
    for (int i = t; i < 8192; i += 256) {
      int f = i >> 6, c = i & 63;
      wbl[i] = Wr[f * 128 + kt * 64 + c];
    }
    __syncthreads();
    f4 part = {0.f, 0.f, 0.f, 0.f};
    {
      f4 u[8];
      #pragma unroll
      for (int rr = 0; rr < 8; ++rr) u[rr] = *(const f4*)&br[kt * 64 + col4];
      for (int f0 = 0; f0 < 64; f0 += 4) {
        f4 h4[8];
        #pragma unroll
        for (int rr = 0; rr < 8; ++rr) h4[rr] = *(const f4*)&hl[(r0 + rr) * 64 + f0];
        #pragma unroll
        for (int ff = 0; ff < 4; ++ff) {
          f4 w4 = *(const f4*)&wbl[(f0 + ff) * 64 + col4];
          #pragma unroll
          for (int rr = 0; rr < 8; ++rr) u[rr] += h4[rr][ff] * w4;
        }
      }
      for (int f0 = 0; f0 < 64; f0 += 4) {
        f4 n4[8];
        #pragma unroll
        for (int rr = 0; rr < 8; ++rr) n4[rr] = *(const f4*)&xl[(r0 + rr) * 64 + f0];
        #pragma unroll
        for (int ff = 0; ff < 4; ++ff) {
          f4 w4 = *(const f4*)&wbl[(64 + f0 + ff) * 64 + col4];
          #pragma unroll
          for (int rr = 0; rr < 8; ++rr) u[rr] += n4[rr][ff] * w4;
        }
      }
      #pragma unroll
      for (int rr = 0; rr < 8; ++rr) {
        int row = b * 128 + r0 + rr;
        if (cntg[row] > 0) part += relu4(u[rr]);
      }
    }
    *(f4*)&wml[rg * 64 + col4] = part;
    __syncthreads();
    for (int off = 8; off; off >>= 1) {
      if (rg < off) {
        f4 v = *(f4*)&wml[rg * 64 + col4] + *(f4*)&wml[(rg + off) * 64 + col4];
        *(f4*)&wml[rg * 64 + col4] = v;
      }
      __syncthreads();
    }
    if (rg == 0) *(f4*)&out12[(size_t)b * 128 + kt * 64 + col4] = *(f4*)&wml[col4];
    __syncthreads();
  }
}

// ================= kC: k8_dec (256 blocks) ---------------------------------
__global__ __launch_bounds__(256) void kC(
    const float* __restrict__ W1, float* __restrict__ ws) {
  int bid = blockIdx.x;
  int t = threadIdx.x;
  int ks = bid & 31, jt = (bid >> 5) & 3, p = bid >> 7;
  const float* hs = ws + OFF_HS + (size_t)p * HS_PSIZE;
  float* pp = ws + OFF_PPRE + (size_t)p * 16384;
  int s0 = ks * 32;
  int s1 = (ks == 31) ? Ss : s0 + 32;   // last chunk: 41 s (f4 groups + pad)
  int j0 = jt * 64;
  __shared__ __attribute__((aligned(16))) float hsl[4][768];  // [s][b*12+k]
  __shared__ __attribute__((aligned(16))) float w1l[4][512];  // [s][l*64+j]
  int jl = (t & 15) * 4, bb = t >> 4;   // group bb: b in {bb, bb+16, bb+32, bb+48}
  f4 acc[4] = {};
  for (int sb = s0; sb < s1; sb += 4) {
    #pragma unroll
    for (int u = 0; u < 2; ++u) {
      int bk = t + 256 * u;
      int b = bk >> 3, k = bk & 7;
      f4 v = *(const f4*)&hs[(size_t)b * HS_BSTRIDE + (size_t)k * HS_KSTRIDE + sb];
      int c = b * 12 + k;
      hsl[0][c] = v[0]; hsl[1][c] = v[1]; hsl[2][c] = v[2]; hsl[3][c] = v[3];
    }
    #pragma unroll
    for (int u = 0; u < 2; ++u) {
      int idx = t + 256 * u;
      int ss = idx >> 7, l = (idx >> 4) & 7, jj = (idx & 15) * 4;
      int s = sb + ss;
      f4 wv = (s < Ss) ? *(const f4*)&W1[(size_t)(s * 8 + l) * 256 + j0 + jj]
                       : (f4){0.f, 0.f, 0.f, 0.f};
      *(f4*)&w1l[ss][l * 64 + jj] = wv;
    }
    __syncthreads();
    #pragma unroll
    for (int ss = 0; ss < 4; ++ss) {
      f4 r[4][2];
      #pragma unroll
      for (int i = 0; i < 4; ++i) {
        int b = bb + 16 * i;
        r[i][0] = *(const f4*)&hsl[ss][b * 12];
        r[i][1] = *(const f4*)&hsl[ss][b * 12 + 4];
      }
      #pragma unroll
      for (int l = 0; l < 8; ++l) {
        f4 wv = *(const f4*)&w1l[ss][l * 64 + jl];
        #pragma unroll
        for (int i = 0; i < 4; ++i) {
          float hv = (l < 4) ? r[i][0][l] : r[i][1][l - 4];
          acc[i] += hv * wv;
        }
      }
    }
    __syncthreads();
  }
  #pragma unroll
  for (int i = 0; i < 4; ++i) {
    int b = bb + 16 * i;
    float* dst = pp + (size_t)b * 256 + j0 + jl;
    atomicAdd(dst + 0, acc[i][0]); atomicAdd(dst + 1, acc[i][1]);
    atomicAdd(dst + 2, acc[i][2]); atomicAdd(dst + 3, acc[i][3]);
  }
}

// ================= kD: k_final with inline BatchNorm ------------------------
__global__ __launch_bounds__(256) void kD(
    const float* __restrict__ b1, const float* __restrict__ bng,
    const float* __restrict__ bnb,
    const float* __restrict__ d1m, const float* __restrict__ d2m,
    const float* __restrict__ se, const float* __restrict__ Wf,
    float* __restrict__ ws, float* __restrict__ out) {
  int b = blockIdx.x, t = threadIdx.x;
  const float* out12 = ws + OFF_OUT12;
  const float* pp0 = ws + OFF_PPRE;
  const float* pp1 = ws + OFF_PPRE + 16384;
  const float* w2f = ws + OFF_W2F;
  const float* wmf = ws + OFF_WMF;
  const float* wsf = ws + OFF_WSF;
  float bj = b1[t];
  float sm0 = 0.f, sq0 = 0.f, sm1 = 0.f, sq1 = 0.f;
  for (int bb = 0; bb < 64; ++bb) {
    float v0 = fmaxf(pp0[bb * 256 + t] + bj, 0.f);
    float v1 = fmaxf(pp1[bb * 256 + t] + bj, 0.f);
    sm0 += v0; sq0 += v0 * v0;
    sm1 += v1; sq1 += v1 * v1;
  }
  float m0 = sm0 * (1.f / 64.f);
  float var0 = fmaxf(sq0 * (1.f / 64.f) - m0 * m0, 0.f);
  float rstd0 = rsqrtf(var0 + 1e-5f);
  float sc0 = bng[t] * rstd0, sh0 = bnb[t] - m0 * sc0;
  float m1 = sm1 * (1.f / 64.f);
  float var1 = fmaxf(sq1 * (1.f / 64.f) - m1 * m1, 0.f);
  float rstd1 = rsqrtf(var1 + 1e-5f);
  float sc1 = bng[t] * rstd1, sh1 = bnb[t] - m1 * sc1;
  float val0 = sc0 * fmaxf(pp0[b * 256 + t] + bj, 0.f) + sh0;
  float val1 = sc1 * fmaxf(pp1[b * 256 + t] + bj, 0.f) + sh1;
  float acc = val0 * w2f[t] + val1 * w2f[256 + t];
  if (t < 128) {
    acc += out12[b * 128 + t] * Wf[t];
    acc += out12[8192 + b * 128 + t] * Wf[218 + t];
  }
  if (t < 200) {
    acc += d1m[b * 200 + t] * wmf[t];
    acc += d2m[b * 200 + t] * wmf[200 + t];
  }
  for (int i = t; i < 963; i += 256) acc += se[b * 963 + i] * wsf[i];
  __shared__ float red[256];
  red[t] = acc;
  __syncthreads();
  for (int off = 128; off; off >>= 1) {
    if (t < off) red[t] += red[t + off];
    __syncthreads();
  }
  if (t == 0) out[b] = red[0] + (ws + OFF_CONST)[0];
}

extern "C" void kernel_launch(void* const* d_in, const int* in_sizes, int n_in,
                              void* d_out, int out_size, void* d_ws, size_t ws_size,
                              hipStream_t stream) {
  const float* adj1  = (const float*)d_in[0];
  const float* nodes1= (const float*)d_in[1];
  const float* edges1= (const float*)d_in[2];
  const float* adj2  = (const float*)d_in[3];
  const float* nodes2= (const float*)d_in[4];
  const float* edges2= (const float*)d_in[5];
  const float* d1m   = (const float*)d_in[6];
  const float* d2m   = (const float*)d_in[7];
  const int*   ids1  = (const int*)d_in[8];
  const int*   ids2  = (const int*)d_in[9];
  const float* se    = (const float*)d_in[10];
  const float* we    = (const float*)d_in[11];
  const float* pe    = (const float*)d_in[12];
  const float* lng   = (const float*)d_in[13];
  const float* lnb   = (const float*)d_in[14];
  const float* Wih   = (const float*)d_in[15];
  const float* Whh   = (const float*)d_in[16];
  const float* bih   = (const float*)d_in[17];
  const float* bhh   = (const float*)d_in[18];
  const float* W1    = (const float*)d_in[19];
  const float* b1    = (const float*)d_in[20];
  const float* bng   = (const float*)d_in[21];
  const float* bnb   = (const float*)d_in[22];
  const float* W2    = (const float*)d_in[23];
  const float* b2    = (const float*)d_in[24];
  const float* Wm1   = (const float*)d_in[25];
  const float* We1   = (const float*)d_in[26];
  const float* Wup1  = (const float*)d_in[27];
  const float* bup1  = (const float*)d_in[28];
  const float* Wr1   = (const float*)d_in[29];
  const float* br1   = (const float*)d_in[30];
  const float* Wm2   = (const float*)d_in[31];
  const float* We2   = (const float*)d_in[32];
  const float* Wup2  = (const float*)d_in[33];
  const float* bup2  = (const float*)d_in[34];
  const float* Wr2   = (const float*)d_in[35];
  const float* br2   = (const float*)d_in[36];
  const float* Wmo   = (const float*)d_in[37];
  const float* bmo   = (const float*)d_in[38];
  const float* Wsd   = (const float*)d_in[39];
  const float* bsd   = (const float*)d_in[40];
  const float* Wf    = (const float*)d_in[41];
  const float* bf    = (const float*)d_in[42];
  float* ws = (float*)d_ws;
  float* out = (float*)d_out;

  // A: adjacency prep + protein front-end + W_final fold + zero(pp)
  kA<<<8245, 256, 0, stream>>>(adj1, adj2, edges1, edges2, We1, We2,
                               ids1, ids2, we, pe, lng, lnb, Wih, bih, bhh,
                               W2, b2, Wmo, bmo, Wsd, bsd, Wf, bf, ws);
  // B: fused MPNN (128 blocks, in LSTM's shadow) + LSTM scan (32 blocks)
  kB<<<160, 256, 0, stream>>>(nodes1, nodes2, Wm1, Wm2, Wup1, Wup2, bup1, bup2,
                              Wr1, Wr2, br1, br2, Whh, ws);
  // C: dec_W1 split-K GEMM (256 blocks)
  kC<<<256, 256, 0, stream>>>(W1, ws);
  // D: final dot with inline BatchNorm
  kD<<<64, 256, 0, stream>>>(b1, bng, bnb, d1m, d2m, se, Wf, ws, out);
}